// Round 12
// baseline (144.135 us; speedup 1.0000x reference)
//
#include <hip/hip_runtime.h>
#include <float.h>

#define K_CODES 1024
#define DIM 64
#define T_LEN 8192
#define N_TOK 131072          // 16 * 8192 tokens
#define LO_SCALE 2048.0f
#define MAGIC 0x5CA1AB1Eu

typedef _Float16 half8 __attribute__((ext_vector_type(8)));  // 4 VGPRs: MFMA A/B frag
typedef float    f32x4 __attribute__((ext_vector_type(4)));  // MFMA C/D frag

#define MFMA16(a, b, c) __builtin_amdgcn_mfma_f32_16x16x32_f16((a), (b), (c), 0, 0, 0)

// Single fused kernel. r6-r11 showed the main loop is pinned at 64-75us across every
// structural variant (B-path, occupancy, ILP, MFMA shape) — but the 2-kernel layout
// costs ~13-18us of bench total vs single-kernel (r5 gap 50us vs r2-r11 gap 62-69us).
// So: fuse prep via device-scope flag sync. Grid 512 = 2 blocks/CU <= capacity ->
// all blocks co-resident, no deadlock. Blocks 0..63 prep tile blockIdx.x, fence,
// release MAGIC flag; everyone loads A-frags (independent of w, overlaps the wait),
// spin-acquires the 64 flags, then runs r10's main loop (best known) unchanged.
__global__ __launch_bounds__(256, 2)
void vq_fused(const float* __restrict__ in,
              const float* __restrict__ cb,
              _Float16* __restrict__ w,
              float* __restrict__ wesq,
              unsigned int* __restrict__ flags,
              float* __restrict__ out) {
    __shared__ float esq_s[K_CODES];   // 4 KB (scaled x2048)
    __shared__ int   idx_s[256];
    __shared__ float part[128];

    const int tid  = threadIdx.x;
    const int wave = tid >> 6;
    const int lane = tid & 63;
    const int lo4  = lane & 15;   // code residue (C col) / token residue (A m)
    const int quad = lane >> 4;   // k-octet selector; token-row group in C

    // ---- phase 0: prep (blocks 0..63 only), tile ct = blockIdx.x ----
    // Tile ct (16 codes) = 4 KB: hi[q][code][j], lo(x2048) at +1024. wesq = 2048*||e||^2.
    if (blockIdx.x < 64) {
        const int ct   = blockIdx.x;
        const int halF = tid >> 7;
        const int rr   = tid & 127;
        const int q    = rr >> 4;
        const int code = rr & 15;

        const float* src = cb + (size_t)(ct * 16 + code) * DIM + q * 8;
        float4 v0 = *reinterpret_cast<const float4*>(src);
        float4 v1 = *reinterpret_cast<const float4*>(src + 4);
        float x[8] = {v0.x, v0.y, v0.z, v0.w, v1.x, v1.y, v1.z, v1.w};

        half8 o;
        float psum = 0.0f;
        #pragma unroll
        for (int j = 0; j < 8; ++j) {
            _Float16 h = (_Float16)x[j];
            o[j] = halF ? (_Float16)((x[j] - (float)h) * LO_SCALE) : h;  // exact residual
            psum = fmaf(x[j], x[j], psum);
        }
        *reinterpret_cast<half8*>(w + (size_t)ct * 2048 + halF * 1024 + q * 128 + code * 8) = o;

        if (halF == 0) part[rr] = psum;
        __syncthreads();                  // w stores drained (vmcnt0) + part visible
        if (tid < 16) {
            float s = 0.0f;
            #pragma unroll
            for (int q2 = 0; q2 < 8; ++q2) s += part[q2 * 16 + tid];
            wesq[ct * 16 + tid] = s * LO_SCALE;
        }
        __syncthreads();                  // wesq stores drained before the fence
        if (tid == 0) {
            __threadfence();              // device-scope release of w + wesq
            __hip_atomic_store(&flags[ct], MAGIC, __ATOMIC_RELEASE,
                               __HIP_MEMORY_SCOPE_AGENT);
        }
    }

    // ---- A fragments (independent of w -> overlaps the prep wait) ----
    const int strip = blockIdx.x * 256 + wave * 64;   // 64 tokens per wave
    const int b  = strip >> 13;
    const int t0 = strip & 8191;
    const float* xin = in + (size_t)b * DIM * T_LEN + t0;
    half8 a_h[4][2], a_hs[4][2], a_l[4][2];
    #pragma unroll
    for (int mt = 0; mt < 4; ++mt) {
        #pragma unroll
        for (int s = 0; s < 2; ++s) {
            half8 hh, hs, ll;
            #pragma unroll
            for (int j = 0; j < 8; ++j) {
                const int d = s * 32 + quad * 8 + j;
                float xv = -2.0f * xin[(size_t)d * T_LEN + mt * 16 + lo4];
                _Float16 h = (_Float16)xv;
                hh[j] = h;
                hs[j] = (_Float16)((float)h * LO_SCALE);   // exact exponent shift
                ll[j] = (_Float16)((xv - (float)h) * LO_SCALE);
            }
            a_h[mt][s] = hh;
            a_hs[mt][s] = hs;
            a_l[mt][s] = ll;
        }
    }

    // ---- wait for all 64 prep flags (acquire), then stage esq ----
    if (tid < 64) {
        while (__hip_atomic_load(&flags[tid], __ATOMIC_ACQUIRE,
                                 __HIP_MEMORY_SCOPE_AGENT) != MAGIC)
            __builtin_amdgcn_s_sleep(8);
    }
    __syncthreads();
    for (int k = tid; k < K_CODES; k += 256) esq_s[k] = wesq[k];
    __syncthreads();

    // ---- main loop: EXACT r10 body (best known: 64.6us) ----
    float best[16];
    int   bidx[16];
    #pragma unroll
    for (int i = 0; i < 16; ++i) { best[i] = FLT_MAX; bidx[i] = 0; }

    const _Float16* wb = w + (size_t)lane * 8;

    half8 Ah0, Ah1, Al0, Al1, Bh0, Bh1, Bl0, Bl1;
    float Ae, Be;
    auto loadB = [&](int ct, half8& h0, half8& h1, half8& l0, half8& l1, float& es) {
        const _Float16* p = wb + (size_t)ct * 2048;
        h0 = *reinterpret_cast<const half8*>(p);          // hi, k 0..31
        h1 = *reinterpret_cast<const half8*>(p + 512);    // hi, k 32..63
        l0 = *reinterpret_cast<const half8*>(p + 1024);   // lo(x2048), k 0..31
        l1 = *reinterpret_cast<const half8*>(p + 1536);   // lo(x2048), k 32..63
        es = esq_s[ct * 16 + lo4];
    };
    auto step = [&](const half8& h0, const half8& h1, const half8& l0,
                    const half8& l1, float es, int ct) {
        const int code = ct * 16 + lo4;
        #pragma unroll
        for (int mt = 0; mt < 4; ++mt) {
            f32x4 c = {es, es, es, es};        // 2048*||e||^2
            c = MFMA16(a_hs[mt][0], h0, c);    // 2048*ah*bh
            c = MFMA16(a_hs[mt][1], h1, c);
            c = MFMA16(a_h[mt][0], l0, c);     // ah*(2048*bl)
            c = MFMA16(a_h[mt][1], l1, c);
            c = MFMA16(a_l[mt][0], h0, c);     // (2048*al)*bh
            c = MFMA16(a_l[mt][1], h1, c);
            #pragma unroll
            for (int r = 0; r < 4; ++r) {
                float sc = c[r];
                const int i = mt * 4 + r;
                bool lt = sc < best[i];         // strict <: first occurrence wins
                best[i] = lt ? sc : best[i];
                bidx[i] = lt ? code : bidx[i];
            }
        }
    };

    loadB(0, Ah0, Ah1, Al0, Al1, Ae);
    loadB(1, Bh0, Bh1, Bl0, Bl1, Be);
    for (int p = 0; p < 31; ++p) {
        step(Ah0, Ah1, Al0, Al1, Ae, 2 * p);
        loadB(2 * p + 2, Ah0, Ah1, Al0, Al1, Ae);
        step(Bh0, Bh1, Bl0, Bl1, Be, 2 * p + 1);
        loadB(2 * p + 3, Bh0, Bh1, Bl0, Bl1, Be);
    }
    step(Ah0, Ah1, Al0, Al1, Ae, 62);
    step(Bh0, Bh1, Bl0, Bl1, Be, 63);

    // ---- cross-lane merge over the 16 code-residue lanes ----
    #pragma unroll
    for (int i = 0; i < 16; ++i) {
        float s = best[i];
        int  ix = bidx[i];
        #pragma unroll
        for (int off = 1; off < 16; off <<= 1) {
            float s2 = __shfl_xor(s, off, 64);
            int  ix2 = __shfl_xor(ix, off, 64);
            bool take = (s2 < s) || (s2 == s && ix2 < ix);  // tie -> lower index
            s  = take ? s2 : s;
            ix = take ? ix2 : ix;
        }
        if (lo4 == 0) {
            // token_local = mt*16 + quad*4 + r,  mt = i>>2, r = i&3
            idx_s[wave * 64 + (i >> 2) * 16 + quad * 4 + (i & 3)] = ix;
        }
    }
    __syncthreads();

    // ---- epilogue: 1 thread per token, gather exact fp32 row + coalesced stores ----
    const int token = blockIdx.x * 256 + tid;
    const int tb = token >> 13;
    const int tt = token & 8191;
    const int my_idx = idx_s[tid];

    out[(size_t)N_TOK * DIM + token] = (float)my_idx;   // index output

    const float* crow = cb + (size_t)my_idx * DIM;
    float* outv = out + (size_t)tb * DIM * T_LEN + tt;
    #pragma unroll
    for (int d0 = 0; d0 < DIM; d0 += 4) {
        float4 v = *reinterpret_cast<const float4*>(crow + d0);  // L2-hot gather
        outv[(size_t)(d0 + 0) * T_LEN] = v.x;
        outv[(size_t)(d0 + 1) * T_LEN] = v.y;
        outv[(size_t)(d0 + 2) * T_LEN] = v.z;
        outv[(size_t)(d0 + 3) * T_LEN] = v.w;
    }
}

extern "C" void kernel_launch(void* const* d_in, const int* in_sizes, int n_in,
                              void* d_out, int out_size, void* d_ws, size_t ws_size,
                              hipStream_t stream) {
    const float* in = (const float*)d_in[0];   // (16, 64, 8192) fp32
    const float* cb = (const float*)d_in[1];   // (1024, 64) fp32
    float* out = (float*)d_out;

    _Float16*    w     = (_Float16*)d_ws;                           // 256 KB
    float*       wesq  = (float*)((char*)d_ws + 64 * 4096);         // 4 KB
    unsigned int* flags = (unsigned int*)((char*)d_ws + 64 * 4096 + 4096);  // 256 B

    vq_fused<<<dim3(N_TOK / 256), dim3(256), 0, stream>>>(in, cb, w, wesq, flags, out);
}